// Round 1
// baseline (353.505 us; speedup 1.0000x reference)
//
#include <hip/hip_runtime.h>

typedef unsigned short ushort_t;
typedef __attribute__((ext_vector_type(8))) short short8;
typedef __attribute__((ext_vector_type(4))) float f32x4;
typedef __attribute__((ext_vector_type(4))) int int4v;

#define RNUM 8
#define FDIM 128
#define KDIM 1152   // 9 * 128: slots 0..7 = per-relation means, slot 8 = x / relu(h)

__device__ __forceinline__ float bf2f(ushort_t u) {
    union { unsigned int i; float f; } x;
    x.i = ((unsigned int)u) << 16;
    return x.f;
}
__device__ __forceinline__ ushort_t f2bf(float f) {
    union { float f; unsigned int i; } x;
    x.f = f;
    unsigned int u = x.i;
    u += 0x7fffu + ((u >> 16) & 1u);   // round-to-nearest-even
    return (ushort_t)(u >> 16);
}

// async global->LDS, 16B per lane; LDS side must be wave-contiguous
__device__ __forceinline__ void gl_lds16(const void* g, void* s) {
    __builtin_amdgcn_global_load_lds(
        (const __attribute__((address_space(1))) unsigned int*)g,
        (__attribute__((address_space(3))) unsigned int*)s, 16, 0, 0);
}

// ---------------- linked-list segment index ----------------
// head[seg] -> most recent edge id, next[i] -> previous edge with same seg.

__global__ void init_head(int* __restrict__ head, int n) {
    int i = blockIdx.x * 256 + threadIdx.x;
    if (i < n) head[i] = -1;
}

__global__ void link_kernel(const int* __restrict__ dst, const int* __restrict__ et,
                            int* head, int* __restrict__ nxt, int E) {
    int i = blockIdx.x * 256 + threadIdx.x;
    if (i < E) {
        int seg = dst[i] * RNUM + et[i];
        nxt[i] = atomicExch(&head[seg], i);
    }
}

// ------- weight transpose + bf16 cast: Wt[r][h][f] = bf16(W[r][f][h]), r=8 -> root -------

__global__ __launch_bounds__(256) void transpose_w(const float* __restrict__ rel_w,
                                                   const float* __restrict__ root_w,
                                                   ushort_t* __restrict__ Wt) {
    int r = blockIdx.x;  // 0..8
    const float* src = (r < 8) ? (rel_w + r * 16384) : root_w;
    __shared__ ushort_t t[128 * 130];
    for (int idx = threadIdx.x; idx < 16384; idx += 256)
        t[(idx >> 7) * 130 + (idx & 127)] = f2bf(src[idx]);
    __syncthreads();
    ushort_t* d = Wt + r * 16384;
    for (int idx = threadIdx.x; idx < 16384; idx += 256)
        d[idx] = t[(idx & 127) * 130 + (idx >> 7)];
}

// ---------------- cast x (f32) into Mx slot 8 ----------------

__global__ void cast_x(const float* __restrict__ x, ushort_t* __restrict__ Mx, int total) {
    int i = (blockIdx.x * 256 + threadIdx.x) * 8;
    if (i >= total) return;
    float4 v0 = *(const float4*)(x + i);
    float4 v1 = *(const float4*)(x + i + 4);
    ushort_t o[8] = {f2bf(v0.x), f2bf(v0.y), f2bf(v0.z), f2bf(v0.w),
                     f2bf(v1.x), f2bf(v1.y), f2bf(v1.z), f2bf(v1.w)};
    int row = i >> 7, col = i & 127;
    *(int4v*)(Mx + (size_t)row * KDIM + 1024 + col) = *(int4v*)o;
}

// ---------------- phase A: per-(node,rel) segment means ----------------
// One quarter-wave (16 lanes x 16B) handles FOUR consecutive segments with
// their chains interleaved, and the next edge's (esrc,nxt) metadata is
// prefetched while the current edge's row gather is in flight. This lifts
// in-flight gathers per quarter-wave from 1 to 4 and collapses the per-edge
// critical path from meta-latency + gather-latency to ~gather-latency.
// Writes for the 4 segments are 4x256B consecutive chunks (coalesced).

__global__ __launch_bounds__(256) void seg_mean(const int* __restrict__ head,
                                                const int* __restrict__ nxt,
                                                const int* __restrict__ esrc,
                                                ushort_t* Mx, int NSEG) {
    int t = blockIdx.x * 256 + threadIdx.x;
    int g = t >> 4;          // quarter-wave group id
    int l16 = t & 15;
    int segBase = g * 4;
    if (segBase >= NSEG) return;
    const ushort_t* gbase = Mx + 1024 + (size_t)l16 * 8;

    float acc[4][8];
    int cnt[4];
    int j[4], s[4], nx[4];
#pragma unroll
    for (int c = 0; c < 4; ++c) {
        cnt[c] = 0;
#pragma unroll
        for (int k = 0; k < 8; ++k) acc[c][k] = 0.f;
        int sg = segBase + c;
        j[c] = (sg < NSEG) ? head[sg] : -1;
    }
#pragma unroll
    for (int c = 0; c < 4; ++c)
        if (j[c] >= 0) { s[c] = esrc[j[c]]; nx[c] = nxt[j[c]]; }

    // continue while ANY chain active: AND of the 4 ids has sign bit 0
    // iff at least one id is >= 0 (ids are either -1 or valid >= 0).
    while ((j[0] & j[1] & j[2] & j[3]) >= 0) {
        // pass 1: issue all row gathers (up to 4 in flight)
        int4v v[4];
#pragma unroll
        for (int c = 0; c < 4; ++c)
            if (j[c] >= 0) v[c] = *(const int4v*)(gbase + (size_t)s[c] * KDIM);
        // pass 2: prefetch next edges' metadata while gathers are in flight
        int s2[4], nx2[4];
#pragma unroll
        for (int c = 0; c < 4; ++c)
            if (j[c] >= 0 && nx[c] >= 0) { s2[c] = esrc[nx[c]]; nx2[c] = nxt[nx[c]]; }
        // pass 3: accumulate and advance
#pragma unroll
        for (int c = 0; c < 4; ++c) {
            if (j[c] >= 0) {
                const ushort_t* p = (const ushort_t*)&v[c];
#pragma unroll
                for (int k = 0; k < 8; ++k) acc[c][k] += bf2f(p[k]);
                ++cnt[c];
                j[c] = nx[c];
                s[c] = s2[c];
                nx[c] = nx2[c];
            }
        }
    }

#pragma unroll
    for (int c = 0; c < 4; ++c) {
        int sg = segBase + c;
        if (sg < NSEG) {
            float sc = (cnt[c] > 0) ? 1.0f / (float)cnt[c] : 0.f;
            ushort_t ov[8];
#pragma unroll
            for (int k = 0; k < 8; ++k) ov[k] = f2bf(acc[c][k] * sc);
            *(int4v*)(Mx + (size_t)(sg >> 3) * KDIM + (sg & 7) * 128 + l16 * 8) = *(int4v*)ov;
        }
    }
}

// ---------------- phase B: dense GEMM  C[128n x 128h] = Mx[128n x 1152k] @ Wt^T ----------
// A,B staged per r-slot via global_load_lds (16B) into XOR-swizzled contiguous LDS.
// LDS chunk layout: 16B chunk c of row n stored at position c ^ (n & 15).

template <bool FINAL>
__global__ __launch_bounds__(256) void rgcn_gemm(
    const ushort_t* Mx, const ushort_t* __restrict__ Wt,
    const float* __restrict__ bias, float* __restrict__ outF,
    ushort_t* MxOut, int N) {
    __shared__ ushort_t As[128 * 128];
    __shared__ ushort_t Bs[128 * 128];
    int tid = threadIdx.x;
    int wid = tid >> 6, lane = tid & 63;
    int l16 = lane & 15, q = lane >> 4;
    int nodeBase = blockIdx.x * 128;

    f32x4 acc[2][8];
#pragma unroll
    for (int rt = 0; rt < 2; ++rt)
#pragma unroll
        for (int ct = 0; ct < 8; ++ct) acc[rt][ct] = (f32x4){0.f, 0.f, 0.f, 0.f};

    for (int r = 0; r < 9; ++r) {
        __syncthreads();  // previous iteration's LDS reads done
#pragma unroll
        for (int i = 0; i < 8; ++i) {
            int L = i * 256 + tid;          // 16B slot index, wave-contiguous
            int row = L >> 4;               // 0..127
            int c = (L & 15) ^ (row & 15);  // logical chunk for this slot
            gl_lds16(Mx + (size_t)(nodeBase + row) * KDIM + r * 128 + c * 8,
                     (char*)As + (size_t)L * 16);
            gl_lds16(Wt + r * 16384 + row * 128 + c * 8,
                     (char*)Bs + (size_t)L * 16);
        }
        __syncthreads();  // drains vmcnt -> staged data visible
#pragma unroll
        for (int s = 0; s < 4; ++s) {
            int pos = ((s * 4 + q) ^ l16) * 16;
            short8 a0 = *(const short8*)((const char*)As + ((2 * wid + 0) * 16 + l16) * 256 + pos);
            short8 a1 = *(const short8*)((const char*)As + ((2 * wid + 1) * 16 + l16) * 256 + pos);
#pragma unroll
            for (int ct = 0; ct < 8; ++ct) {
                short8 b = *(const short8*)((const char*)Bs + (ct * 16 + l16) * 256 + pos);
                acc[0][ct] = __builtin_amdgcn_mfma_f32_16x16x32_bf16(a0, b, acc[0][ct], 0, 0, 0);
                acc[1][ct] = __builtin_amdgcn_mfma_f32_16x16x32_bf16(a1, b, acc[1][ct], 0, 0, 0);
            }
        }
    }
    // epilogue: C layout col = lane&15, row = q*4 + reg
#pragma unroll
    for (int rt = 0; rt < 2; ++rt) {
#pragma unroll
        for (int ct = 0; ct < 8; ++ct) {
            int h = ct * 16 + l16;
            float bv = bias[h];
#pragma unroll
            for (int reg = 0; reg < 4; ++reg) {
                int node = nodeBase + (2 * wid + rt) * 16 + q * 4 + reg;
                if (node < N) {
                    float v = acc[rt][ct][reg] + bv;
                    if (FINAL) {
                        outF[(size_t)node * FDIM + h] = v;
                    } else {
                        v = fmaxf(v, 0.f);
                        MxOut[(size_t)node * KDIM + 1024 + h] = f2bf(v);
                    }
                }
            }
        }
    }
}

__global__ void copy_emb(const float* __restrict__ e, float* __restrict__ out, int n) {
    int i = blockIdx.x * 256 + threadIdx.x;
    if (i < n) out[i] = e[i];
}

// ---------------- launch ----------------

extern "C" void kernel_launch(void* const* d_in, const int* in_sizes, int n_in,
                              void* d_out, int out_size, void* d_ws, size_t ws_size,
                              hipStream_t stream) {
    const float* x        = (const float*)d_in[0];
    const int* edge_index = (const int*)d_in[1];
    const int* edge_type  = (const int*)d_in[2];
    const float* rel_w0   = (const float*)d_in[3];
    const float* root_w0  = (const float*)d_in[4];
    const float* bias0    = (const float*)d_in[5];
    const float* rel_w1   = (const float*)d_in[6];
    const float* root_w1  = (const float*)d_in[7];
    const float* bias1    = (const float*)d_in[8];
    const float* rel_emb  = (const float*)d_in[9];

    int N = in_sizes[0] / FDIM;   // 50000
    int E = in_sizes[1] / 2;      // 800000
    int NSEG = N * RNUM;          // 400000
    const int* src = edge_index;
    const int* dst = edge_index + E;

    int nb_gemm = (N + 127) / 128;      // 391
    int NPAD = nb_gemm * 128;           // 50048 (staging reads padded rows)

    char* w = (char*)d_ws;
    auto alloc = [&](size_t bytes) -> char* {
        char* p = w;
        w += (bytes + 255) & ~(size_t)255;
        return p;
    };
    int* head    = (int*)alloc((size_t)NSEG * 4);
    int* nxt     = (int*)alloc((size_t)E * 4);
    ushort_t* Wt = (ushort_t*)alloc((size_t)2 * 9 * 16384 * 2);
    ushort_t* Mx = (ushort_t*)alloc((size_t)NPAD * KDIM * 2);   // ~115 MB
    (void)ws_size; (void)n_in; (void)out_size;

    int nb_seg  = (NSEG + 255) / 256;
    int nb_E    = (E + 255) / 256;
    int ngrp    = (NSEG + 3) / 4;                 // 4 segments per quarter-wave
    int nb_mean = (ngrp * 16 + 255) / 256;        // 6250
    int nb_cast = (N * FDIM) / (256 * 8);         // 3125

    init_head<<<nb_seg, 256, 0, stream>>>(head, NSEG);
    link_kernel<<<nb_E, 256, 0, stream>>>(dst, edge_type, head, nxt, E);
    transpose_w<<<9, 256, 0, stream>>>(rel_w0, root_w0, Wt);
    transpose_w<<<9, 256, 0, stream>>>(rel_w1, root_w1, Wt + 9 * 16384);
    cast_x<<<nb_cast, 256, 0, stream>>>(x, Mx, N * FDIM);

    seg_mean<<<nb_mean, 256, 0, stream>>>(head, nxt, src, Mx, NSEG);
    rgcn_gemm<false><<<nb_gemm, 256, 0, stream>>>(Mx, Wt, bias0, nullptr, Mx, N);
    seg_mean<<<nb_mean, 256, 0, stream>>>(head, nxt, src, Mx, NSEG);
    rgcn_gemm<true><<<nb_gemm, 256, 0, stream>>>(Mx, Wt + 9 * 16384, bias1,
                                                 (float*)d_out, nullptr, N);
    copy_emb<<<4, 256, 0, stream>>>(rel_emb, (float*)d_out + (size_t)N * FDIM,
                                    in_sizes[9]);
}